// Round 13
// baseline (153.088 us; speedup 1.0000x reference)
//
#include <hip/hip_runtime.h>
#include <hip/hip_bf16.h>

// GlassBlur via permutation composition with a WINDOWED DIRECT CHASE fused
// into the final blur.
// P = Q_{u=0} o Q_{u=1} o ... o Q_{u=222} (swap-row u=0 earliest), so
// P(p) = Q_0(Q_1(...Q_222(p))): chase applies row perms latest-first
// (u = 222 -> 0); perm u touches only rows [222-u, 224-u] (window rising as u
// decreases). A value that moves DOWN exits the window forever -> ~3-5 leaf
// lookups per entry.
// Pipeline: build (row perms -> leaves) -> blur1 -> final (chase 12-row P
// window in-block, then gather+blur all 3 channels). Fallback (small d_ws):
// build -> blur1 -> chaseP -> apply -> blur2.
#define KW0 0.91921792f
#define KW1 0.04038762f
#define KW2 3.42560e-6f

#define HH 224
#define WW 224
#define NSW 49729
#define LEAF_SLOT 676       // 3*224 + 4 pad (u16), values 256-encoded
#define LEAF_IMG 150748     // 223 * 676 u16 per image
#define P_STRIDE 50176

// ---------------- build: pack idx -> register-window row perms -> leaves --------------
// grid (7, 64), 256 threads, 47KB LDS.
__global__ __launch_bounds__(256) void build_kernel(const int* __restrict__ deltas,
                                                    unsigned short* __restrict__ leafG) {
    const int j = blockIdx.x;
    const int b = blockIdx.y;
    const int U = j * 32;

    __shared__ __align__(16) unsigned short smA[32 * LEAF_SLOT];   // 43264 B
    __shared__ unsigned pk[32 * 29];                               //  3712 B

    const int tid = threadIdx.x;
    const int u = U + tid;

    // ---- pack: idx = clamp(dy)*4 + clamp(dx), 8 nibbles per u32 ----
    {
        const int2* Dbase = (const int2*)deltas + (size_t)b * NSW + (size_t)U * 223;
        for (int w = tid; w < 32 * 28; w += 256) {
            const int r = w / 28, k = w - r * 28;
            if (U + r < 223) {
                const int base = r * 223 + 8 * k;
                unsigned word = 0;
#pragma unroll
                for (int jj = 0; jj < 8; ++jj) {
                    const int i = 8 * k + jj;
                    unsigned idx = 5u;                       // identity pad (center)
                    if (i < 223) {
                        int2 d = Dbase[base + jj];
                        unsigned px = (unsigned)d.x, py = (unsigned)d.y;
                        if (U + r == 0) px = min(px, 1u);    // y=223 row clamp
                        if (i == 0) py = min(py, 1u);        // x=223 col clamp
                        idx = px * 4u + py;
                    }
                    word |= idx << (4 * jj);
                }
                pk[r * 29 + k] = word;
            }
        }
    }
    __syncthreads();

    // ---- serial register-window build (lane tid builds row u); values 256-enc ----
    if (tid < 32 && u < 223) {
        const int y = 223 - u;
        const unsigned b0r = (unsigned)(y - 1) << 8;
        const unsigned b1r = (unsigned)y << 8;
        const unsigned b2r = (unsigned)(y + 1) << 8;
        unsigned short* Lf = &smA[tid * LEAF_SLOT];   // [3][224] (+4 pad)
        const unsigned* pkr = &pk[tid * 29];

        unsigned w00 = b0r + 222, w01 = b0r + 223, w02 = b0r + 224;
        unsigned w10 = b1r + 222, w11 = b1r + 223, w12 = b1r + 224;
        unsigned w20 = b2r + 222, w21 = b2r + 223, w22 = b2r + 224;

        unsigned wA_ = pkr[0], wB_ = pkr[1], wC_ = pkr[2];

        // 2-level select: pr = idx>>2, pc = idx&3. Scatter codes:
        // row0:0,1,2  row1:4,(5=center),6  row2:8,9,10.
#define GB_STEP(KK, CA, CB, CC) {                                               \
            const int x_ = 223 - (ibase + (KK));                                \
            const unsigned wsel_ = (((KK) >> 3) == 0) ? wA_                     \
                                 : ((((KK) >> 3) == 1) ? wB_ : wC_);            \
            const unsigned idx_ = (wsel_ >> (4 * ((KK) & 7))) & 15u;            \
            const unsigned pr_ = idx_ >> 2, pc_ = idx_ & 3u;                    \
            const bool pc0_ = (pc_ == 0u), pc1_ = (pc_ == 1u);                  \
            const bool pr0_ = (pr_ == 0u), pr1_ = (pr_ == 1u);                  \
            const unsigned s0_ = pc0_ ? w0##CA : (pc1_ ? w0##CB : w0##CC);      \
            const unsigned s1_ = pc0_ ? w1##CA : (pc1_ ? w1##CB : w1##CC);      \
            const unsigned s2_ = pc0_ ? w2##CA : (pc1_ ? w2##CB : w2##CC);      \
            const unsigned v_ = pr0_ ? s0_ : (pr1_ ? s1_ : s2_);                \
            const unsigned c_ = w1##CB;                                         \
            w0##CA = idx_ == 0u  ? c_ : w0##CA;                                 \
            w0##CB = idx_ == 1u  ? c_ : w0##CB;                                 \
            w0##CC = idx_ == 2u  ? c_ : w0##CC;                                 \
            w1##CA = idx_ == 4u  ? c_ : w1##CA;                                 \
            w1##CC = idx_ == 6u  ? c_ : w1##CC;                                 \
            w2##CA = idx_ == 8u  ? c_ : w2##CA;                                 \
            w2##CB = idx_ == 9u  ? c_ : w2##CB;                                 \
            w2##CC = idx_ == 10u ? c_ : w2##CC;                                 \
            w1##CB = v_;                                                        \
            Lf[x_ + 1]   = (unsigned short)w0##CC;                              \
            Lf[x_ + 225] = (unsigned short)w1##CC;                              \
            Lf[x_ + 449] = (unsigned short)w2##CC;                              \
            w0##CC = b0r + (unsigned)(x_ - 2);                                  \
            w1##CC = b1r + (unsigned)(x_ - 2);                                  \
            w2##CC = b2r + (unsigned)(x_ - 2);                                  \
        }
#define GB_TRIPLE(K0) GB_STEP((K0), 0, 1, 2) GB_STEP((K0)+1, 2, 0, 1) GB_STEP((K0)+2, 1, 2, 0)
        // i=0 junk emissions (Lf[224],Lf[448],Lf[672]) are overwritten by the
        // final col-0/col-1 emits (672 is pad).
        for (int blk = 0; blk < 9; ++blk) {           // i = 0..215
            const int ibase = 24 * blk;
            const unsigned nA_ = pkr[min(3 * blk + 3, 27)];
            const unsigned nB_ = pkr[min(3 * blk + 4, 27)];
            const unsigned nC_ = pkr[min(3 * blk + 5, 27)];
            GB_TRIPLE(0)  GB_TRIPLE(3)  GB_TRIPLE(6)  GB_TRIPLE(9)
            GB_TRIPLE(12) GB_TRIPLE(15) GB_TRIPLE(18) GB_TRIPLE(21)
            wA_ = nA_; wB_ = nB_; wC_ = nC_;
        }
        {                                             // i = 216..222
            const int ibase = 216;
            GB_TRIPLE(0) GB_TRIPLE(3) GB_STEP(6, 0, 1, 2)
        }
        Lf[1] = (unsigned short)w01; Lf[225] = (unsigned short)w11; Lf[449] = (unsigned short)w21;
        Lf[0] = (unsigned short)w00; Lf[224] = (unsigned short)w10; Lf[448] = (unsigned short)w20;
#undef GB_TRIPLE
#undef GB_STEP
    }
    __syncthreads();

    // ---- copy leaves LDS -> global (uint2 coalesced); rows u >= 223 skipped ----
    const int nuT = min(32, 223 - U);
    uint2* dst = (uint2*)(leafG + (size_t)b * LEAF_IMG + (size_t)U * LEAF_SLOT);
    const uint2* srcp = (const uint2*)smA;
    for (int l = tid; l < nuT * (LEAF_SLOT / 4); l += 256) dst[l] = srcp[l];
}

// ---------------- blur1: f32 -> quantize u8 -> blur -> u8 plane (float4 loads) --------
__global__ __launch_bounds__(256) void blur1_kernel(const float* __restrict__ x,
                                                    unsigned char* __restrict__ img) {
    const int rb = blockIdx.x, c = blockIdx.y, b = blockIdx.z;
    const int y0 = rb * 8;
    __shared__ float A[12][WW];
    __shared__ float Bv[8][WW];
    const float* xp = x + ((size_t)(b * 3 + c)) * HH * WW;

    for (int l = threadIdx.x; l < 12 * 56; l += 256) {
        int r = l / 56, k4 = (l - r * 56) * 4;
        int gy = min(max(y0 + r - 2, 0), HH - 1);
        float4 v = *(const float4*)(xp + gy * WW + k4);
        A[r][k4]     = floorf(fminf(fmaxf(v.x * 255.0f, 0.0f), 255.0f));
        A[r][k4 + 1] = floorf(fminf(fmaxf(v.y * 255.0f, 0.0f), 255.0f));
        A[r][k4 + 2] = floorf(fminf(fmaxf(v.z * 255.0f, 0.0f), 255.0f));
        A[r][k4 + 3] = floorf(fminf(fmaxf(v.w * 255.0f, 0.0f), 255.0f));
    }
    __syncthreads();
    for (int l = threadIdx.x; l < 8 * WW; l += 256) {
        int r = l / WW, xx = l - r * WW;
        Bv[r][xx] = KW2 * A[r][xx] + KW1 * A[r + 1][xx] + KW0 * A[r + 2][xx]
                  + KW1 * A[r + 3][xx] + KW2 * A[r + 4][xx];
    }
    __syncthreads();
    unsigned char* op = img + ((size_t)(b * 3 + c)) * HH * WW;
    for (int l = threadIdx.x; l < 8 * WW; l += 256) {
        int r = l / WW, xx = l - r * WW;
        int c0 = max(xx - 2, 0), c1 = max(xx - 1, 0);
        int c3 = min(xx + 1, WW - 1), c4 = min(xx + 2, WW - 1);
        float s = KW2 * Bv[r][c0] + KW1 * Bv[r][c1] + KW0 * Bv[r][xx]
                + KW1 * Bv[r][c3] + KW2 * Bv[r][c4];
        op[(y0 + r) * WW + xx] = (unsigned char)floorf(s);
    }
}

// ---------------- final: chase 12-row P window -> gather+blur 3 channels --------------
// grid (28, 64), 256 threads, ~23KB LDS.
__global__ __launch_bounds__(256) void final_kernel(const unsigned char* __restrict__ img,
                                                    const unsigned short* __restrict__ leafG,
                                                    float* __restrict__ out) {
    const int rb = blockIdx.x, b = blockIdx.y;
    const int y0 = rb * 8;
    __shared__ unsigned short Pwin[12 * WW];   // 224-encoded final cell indices
    __shared__ float A[12][WW];
    __shared__ float Bv[8][WW];
    const unsigned short* L = leafG + (size_t)b * LEAF_IMG;
    const int tid = threadIdx.x;

    // ---- chase: 12*224 entries, 11 chains/thread (stride 256) ----
    {
        unsigned rv[11], cv[11]; bool done[11]; int us[11];
        int umax = -1;
#pragma unroll
        for (int t = 0; t < 11; ++t) {
            const int e = tid + t * 256;
            const bool has = e < 12 * WW;
            const int ec = has ? e : 0;
            const int rr = ec / WW, xx = ec - (ec / WW) * WW;
            const int gy = min(max(y0 + rr - 2, 0), HH - 1);
            rv[t] = (unsigned)gy;
            cv[t] = (unsigned)xx;
            us[t] = has ? min(222, 224 - gy) : -1;
            done[t] = !has;
            if (has) umax = max(umax, us[t]);
        }
        for (int u = umax; u >= 0; --u) {
            const unsigned short* Lu = L + u * LEAF_SLOT;
            const int bot = 222 - u;
            bool all = true;
#pragma unroll
            for (int t = 0; t < 11; ++t) {
                if (!done[t] && u <= us[t]) {
                    if ((int)rv[t] < bot) done[t] = true;
                    else {
                        const unsigned q = Lu[__mul24((int)rv[t] - bot, 224) + (int)cv[t]];
                        rv[t] = q >> 8;
                        cv[t] = q & 255u;
                    }
                }
                all = all && done[t];
            }
            if (all) break;
        }
#pragma unroll
        for (int t = 0; t < 11; ++t) {
            const int e = tid + t * 256;
            if (e < 12 * WW)
                Pwin[e] = (unsigned short)(__mul24((int)rv[t], 224) + (int)cv[t]);
        }
    }
    __syncthreads();

    // ---- per channel: gather at Pwin, vertical blur, horizontal blur + store ----
    for (int c = 0; c < 3; ++c) {
        const unsigned char* ip = img + ((size_t)(b * 3 + c)) * HH * WW;
        for (int l = tid; l < 12 * WW; l += 256) {
            int r = l / WW, xx = l - (l / WW) * WW;
            A[r][xx] = (float)ip[Pwin[l]];
        }
        __syncthreads();
        for (int l = tid; l < 8 * WW; l += 256) {
            int r = l / WW, xx = l - (l / WW) * WW;
            Bv[r][xx] = KW2 * A[r][xx] + KW1 * A[r + 1][xx] + KW0 * A[r + 2][xx]
                      + KW1 * A[r + 3][xx] + KW2 * A[r + 4][xx];
        }
        __syncthreads();
        float* op = out + ((size_t)(b * 3 + c)) * HH * WW;
        for (int l = tid; l < 8 * WW; l += 256) {
            int r = l / WW, xx = l - (l / WW) * WW;
            int c0 = max(xx - 2, 0), c1 = max(xx - 1, 0);
            int c3 = min(xx + 1, WW - 1), c4 = min(xx + 2, WW - 1);
            float s = KW2 * Bv[r][c0] + KW1 * Bv[r][c1] + KW0 * Bv[r][xx]
                    + KW1 * Bv[r][c3] + KW2 * Bv[r][c4];
            s = fminf(fmaxf(s, 0.0f), 255.0f);
            op[(y0 + r) * WW + xx] = floorf(s) / 255.0f;
        }
        __syncthreads();
    }
}

// ================= fallback path (small d_ws): R12's proven kernels =================
__global__ __launch_bounds__(256) void chaseP_kernel(const unsigned short* __restrict__ leafG,
                                                     unsigned short* __restrict__ P) {
    const int b = blockIdx.y;
    const int base = blockIdx.x * 2048;
    const unsigned short* L = leafG + (size_t)b * LEAF_IMG;
    unsigned short* Pb = P + (size_t)b * P_STRIDE;
    const int e0 = base + (int)threadIdx.x * 8;
    if (e0 >= P_STRIDE) return;

    unsigned rv[8], cv[8]; bool done[8]; int us[8];
    const int pr0 = e0 / 224, pc0 = e0 - pr0 * 224;
    int umax = -1;
#pragma unroll
    for (int t = 0; t < 8; ++t) {
        const int pc = pc0 + t;
        const int pr = pr0 + (pc >= 224 ? 1 : 0);
        rv[t] = (unsigned)pr;
        cv[t] = (unsigned)(pc >= 224 ? pc - 224 : pc);
        us[t] = min(222, 224 - pr);
        done[t] = false;
        umax = max(umax, us[t]);
    }
    for (int u = umax; u >= 0; --u) {
        const unsigned short* Lu = L + u * LEAF_SLOT;
        const int bot = 222 - u;
        bool all = true;
#pragma unroll
        for (int t = 0; t < 8; ++t) {
            if (!done[t] && u <= us[t]) {
                if ((int)rv[t] < bot) done[t] = true;
                else {
                    const unsigned q = Lu[__mul24((int)rv[t] - bot, 224) + (int)cv[t]];
                    rv[t] = q >> 8;
                    cv[t] = q & 255u;
                }
            }
            all = all && done[t];
        }
        if (all) break;
    }
    unsigned res[8];
#pragma unroll
    for (int t = 0; t < 8; ++t)
        res[t] = (unsigned)(__mul24((int)rv[t], 224) + (int)cv[t]);
    uint4 v;
    v.x = res[0] | (res[1] << 16);
    v.y = res[2] | (res[3] << 16);
    v.z = res[4] | (res[5] << 16);
    v.w = res[6] | (res[7] << 16);
    *(uint4*)(Pb + e0) = v;
}

__global__ __launch_bounds__(256) void apply_kernel(unsigned char* __restrict__ img,
                                                    const unsigned short* __restrict__ P) {
    const int plane = blockIdx.x;
    const int b = plane / 3;
    __shared__ __align__(16) unsigned char im[HH * WW];
    unsigned char* g = img + (size_t)plane * (HH * WW);
    for (int l = threadIdx.x; l < (HH * WW) / 16; l += 256)
        ((int4*)im)[l] = ((const int4*)g)[l];
    __syncthreads();
    const unsigned short* Pp = P + (size_t)b * P_STRIDE;
    for (int t = threadIdx.x; t < (HH * WW) / 8; t += 256) {
        uint4 pe = ((const uint4*)Pp)[t];
        unsigned e0 = pe.x & 0xffffu, e1 = pe.x >> 16;
        unsigned e2 = pe.y & 0xffffu, e3 = pe.y >> 16;
        unsigned e4 = pe.z & 0xffffu, e5 = pe.z >> 16;
        unsigned e6 = pe.w & 0xffffu, e7 = pe.w >> 16;
        unsigned lo = (unsigned)im[e0] | ((unsigned)im[e1] << 8)
                    | ((unsigned)im[e2] << 16) | ((unsigned)im[e3] << 24);
        unsigned hi = (unsigned)im[e4] | ((unsigned)im[e5] << 8)
                    | ((unsigned)im[e6] << 16) | ((unsigned)im[e7] << 24);
        ((uint2*)g)[t] = make_uint2(lo, hi);
    }
}

__global__ __launch_bounds__(256) void blur2_kernel(const unsigned char* __restrict__ img,
                                                    float* __restrict__ out) {
    const int rb = blockIdx.x, c = blockIdx.y, b = blockIdx.z;
    const int y0 = rb * 8;
    __shared__ float A[12][WW];
    __shared__ float Bv[8][WW];
    const unsigned char* ip = img + ((size_t)(b * 3 + c)) * HH * WW;

    for (int l = threadIdx.x; l < 12 * WW; l += 256) {
        int r = l / WW, xx = l - r * WW;
        int gy = min(max(y0 + r - 2, 0), HH - 1);
        A[r][xx] = (float)ip[gy * WW + xx];
    }
    __syncthreads();
    for (int l = threadIdx.x; l < 8 * WW; l += 256) {
        int r = l / WW, xx = l - r * WW;
        Bv[r][xx] = KW2 * A[r][xx] + KW1 * A[r + 1][xx] + KW0 * A[r + 2][xx]
                  + KW1 * A[r + 3][xx] + KW2 * A[r + 4][xx];
    }
    __syncthreads();
    float* op = out + ((size_t)(b * 3 + c)) * HH * WW;
    for (int l = threadIdx.x; l < 8 * WW; l += 256) {
        int r = l / WW, xx = l - r * WW;
        int c0 = max(xx - 2, 0), c1 = max(xx - 1, 0);
        int c3 = min(xx + 1, WW - 1), c4 = min(xx + 2, WW - 1);
        float s = KW2 * Bv[r][c0] + KW1 * Bv[r][c1] + KW0 * Bv[r][xx]
                + KW1 * Bv[r][c3] + KW2 * Bv[r][c4];
        s = fminf(fmaxf(s, 0.0f), 255.0f);
        op[(y0 + r) * WW + xx] = floorf(s) / 255.0f;
    }
}

extern "C" void kernel_launch(void* const* d_in, const int* in_sizes, int n_in,
                              void* d_out, int out_size, void* d_ws, size_t ws_size,
                              hipStream_t stream) {
    const float* x      = (const float*)d_in[0];
    const int*   deltas = (const int*)d_in[1];
    float*       out    = (float*)d_out;
    unsigned char* img  = (unsigned char*)d_ws;                     // 9,633,792 B

    const size_t imgBytes  = 9633792;
    const size_t leafBytes = (size_t)64 * LEAF_IMG * 2;             // 19,295,744 B
    const bool big_ws = ws_size >= imgBytes + leafBytes;

    if (big_ws) {
        // leafG in d_ws -> final kernel can write all of d_out with no aliasing
        unsigned short* leafG = (unsigned short*)(img + imgBytes);
        build_kernel<<<dim3(7, 64), 256, 0, stream>>>(deltas, leafG);
        blur1_kernel<<<dim3(28, 3, 64), 256, 0, stream>>>(x, img);
        final_kernel<<<dim3(28, 64), 256, 0, stream>>>(img, leafG, out);
    } else {
        // fallback: leafG + P in d_out scratch (dead before blur2's write)
        unsigned short* leafG = (unsigned short*)d_out;
        unsigned short* pF    = leafG + (size_t)64 * LEAF_IMG;
        build_kernel<<<dim3(7, 64), 256, 0, stream>>>(deltas, leafG);
        blur1_kernel<<<dim3(28, 3, 64), 256, 0, stream>>>(x, img);
        chaseP_kernel<<<dim3(25, 64), 256, 0, stream>>>(leafG, pF);
        apply_kernel<<<dim3(192), 256, 0, stream>>>(img, pF);
        blur2_kernel<<<dim3(28, 3, 64), 256, 0, stream>>>(img, out);
    }
}

// Round 14
// 109.828 us; speedup vs baseline: 1.3939x; 1.3939x over previous
//
#include <hip/hip_runtime.h>
#include <hip/hip_bf16.h>

// GlassBlur via permutation composition with a WINDOWED DIRECT CHASE.
// P = Q_{u=0} o ... o Q_{u=222} (swap-row u=0 earliest): chase applies row
// perms latest-first (u = 222 -> 0); perm u touches only rows [222-u, 224-u]
// (window rising as u decreases); a value that moves DOWN is final.
// => ~3-5 leaf lookups per entry, chased directly from per-row leaves.
// Launch order build -> chaseP (leafG L2-hot) -> blur1 -> blur2_apply.
#define KW0 0.91921792f
#define KW1 0.04038762f
#define KW2 3.42560e-6f

#define HH 224
#define WW 224
#define NSW 49729
#define LEAF_SLOT 676       // 3*224 + 4 pad (u16), values 256-encoded
#define LEAF_IMG 150748     // 223 * 676 u16 per image
#define P_STRIDE 50176

// ---------------- build: pack idx -> register-window row perms -> leaves --------------
// grid (7, 64), 256 threads, 47KB LDS.
__global__ __launch_bounds__(256) void build_kernel(const int* __restrict__ deltas,
                                                    unsigned short* __restrict__ leafG) {
    const int j = blockIdx.x;
    const int b = blockIdx.y;
    const int U = j * 32;

    __shared__ __align__(16) unsigned short smA[32 * LEAF_SLOT];   // 43264 B
    __shared__ unsigned pk[32 * 29];                               //  3712 B

    const int tid = threadIdx.x;
    const int u = U + tid;

    // ---- pack: idx = clamp(dy)*4 + clamp(dx), 8 nibbles per u32 ----
    {
        const int2* Dbase = (const int2*)deltas + (size_t)b * NSW + (size_t)U * 223;
        for (int w = tid; w < 32 * 28; w += 256) {
            const int r = w / 28, k = w - r * 28;
            if (U + r < 223) {
                const int base = r * 223 + 8 * k;
                unsigned word = 0;
#pragma unroll
                for (int jj = 0; jj < 8; ++jj) {
                    const int i = 8 * k + jj;
                    unsigned idx = 5u;                       // identity pad (center)
                    if (i < 223) {
                        int2 d = Dbase[base + jj];
                        unsigned px = (unsigned)d.x, py = (unsigned)d.y;
                        if (U + r == 0) px = min(px, 1u);    // y=223 row clamp
                        if (i == 0) py = min(py, 1u);        // x=223 col clamp
                        idx = px * 4u + py;
                    }
                    word |= idx << (4 * jj);
                }
                pk[r * 29 + k] = word;
            }
        }
    }
    __syncthreads();

    // ---- serial register-window build (lane tid builds row u); values 256-enc ----
    if (tid < 32 && u < 223) {
        const int y = 223 - u;
        const unsigned b0r = (unsigned)(y - 1) << 8;
        const unsigned b1r = (unsigned)y << 8;
        const unsigned b2r = (unsigned)(y + 1) << 8;
        unsigned short* Lf = &smA[tid * LEAF_SLOT];   // [3][224] (+4 pad)
        const unsigned* pkr = &pk[tid * 29];

        unsigned w00 = b0r + 222, w01 = b0r + 223, w02 = b0r + 224;
        unsigned w10 = b1r + 222, w11 = b1r + 223, w12 = b1r + 224;
        unsigned w20 = b2r + 222, w21 = b2r + 223, w22 = b2r + 224;

        unsigned wA_ = pkr[0], wB_ = pkr[1], wC_ = pkr[2];

        // 2-level select: pr = idx>>2, pc = idx&3. Scatter codes:
        // row0:0,1,2  row1:4,(5=center),6  row2:8,9,10.
#define GB_STEP(KK, CA, CB, CC) {                                               \
            const int x_ = 223 - (ibase + (KK));                                \
            const unsigned wsel_ = (((KK) >> 3) == 0) ? wA_                     \
                                 : ((((KK) >> 3) == 1) ? wB_ : wC_);            \
            const unsigned idx_ = (wsel_ >> (4 * ((KK) & 7))) & 15u;            \
            const unsigned pr_ = idx_ >> 2, pc_ = idx_ & 3u;                    \
            const bool pc0_ = (pc_ == 0u), pc1_ = (pc_ == 1u);                  \
            const bool pr0_ = (pr_ == 0u), pr1_ = (pr_ == 1u);                  \
            const unsigned s0_ = pc0_ ? w0##CA : (pc1_ ? w0##CB : w0##CC);      \
            const unsigned s1_ = pc0_ ? w1##CA : (pc1_ ? w1##CB : w1##CC);      \
            const unsigned s2_ = pc0_ ? w2##CA : (pc1_ ? w2##CB : w2##CC);      \
            const unsigned v_ = pr0_ ? s0_ : (pr1_ ? s1_ : s2_);                \
            const unsigned c_ = w1##CB;                                         \
            w0##CA = idx_ == 0u  ? c_ : w0##CA;                                 \
            w0##CB = idx_ == 1u  ? c_ : w0##CB;                                 \
            w0##CC = idx_ == 2u  ? c_ : w0##CC;                                 \
            w1##CA = idx_ == 4u  ? c_ : w1##CA;                                 \
            w1##CC = idx_ == 6u  ? c_ : w1##CC;                                 \
            w2##CA = idx_ == 8u  ? c_ : w2##CA;                                 \
            w2##CB = idx_ == 9u  ? c_ : w2##CB;                                 \
            w2##CC = idx_ == 10u ? c_ : w2##CC;                                 \
            w1##CB = v_;                                                        \
            Lf[x_ + 1]   = (unsigned short)w0##CC;                              \
            Lf[x_ + 225] = (unsigned short)w1##CC;                              \
            Lf[x_ + 449] = (unsigned short)w2##CC;                              \
            w0##CC = b0r + (unsigned)(x_ - 2);                                  \
            w1##CC = b1r + (unsigned)(x_ - 2);                                  \
            w2##CC = b2r + (unsigned)(x_ - 2);                                  \
        }
#define GB_TRIPLE(K0) GB_STEP((K0), 0, 1, 2) GB_STEP((K0)+1, 2, 0, 1) GB_STEP((K0)+2, 1, 2, 0)
        // i=0 junk emissions (Lf[224],Lf[448],Lf[672]) are overwritten by the
        // final col-0/col-1 emits (672 is pad).
        for (int blk = 0; blk < 9; ++blk) {           // i = 0..215
            const int ibase = 24 * blk;
            const unsigned nA_ = pkr[min(3 * blk + 3, 27)];
            const unsigned nB_ = pkr[min(3 * blk + 4, 27)];
            const unsigned nC_ = pkr[min(3 * blk + 5, 27)];
            GB_TRIPLE(0)  GB_TRIPLE(3)  GB_TRIPLE(6)  GB_TRIPLE(9)
            GB_TRIPLE(12) GB_TRIPLE(15) GB_TRIPLE(18) GB_TRIPLE(21)
            wA_ = nA_; wB_ = nB_; wC_ = nC_;
        }
        {                                             // i = 216..222
            const int ibase = 216;
            GB_TRIPLE(0) GB_TRIPLE(3) GB_STEP(6, 0, 1, 2)
        }
        Lf[1] = (unsigned short)w01; Lf[225] = (unsigned short)w11; Lf[449] = (unsigned short)w21;
        Lf[0] = (unsigned short)w00; Lf[224] = (unsigned short)w10; Lf[448] = (unsigned short)w20;
#undef GB_TRIPLE
#undef GB_STEP
    }
    __syncthreads();

    // ---- copy leaves LDS -> global (uint2 coalesced); rows u >= 223 skipped ----
    const int nuT = min(32, 223 - U);
    uint2* dst = (uint2*)(leafG + (size_t)b * LEAF_IMG + (size_t)U * LEAF_SLOT);
    const uint2* srcp = (const uint2*)smA;
    for (int l = tid; l < nuT * (LEAF_SLOT / 4); l += 256) dst[l] = srcp[l];
}

// ---------------- chaseP: windowed direct chase, leaves (L2-hot) -> P -----------------
// grid (25, 64), 256 threads, no LDS. Each thread: 8 consecutive entries.
__global__ __launch_bounds__(256) void chaseP_kernel(const unsigned short* __restrict__ leafG,
                                                     unsigned short* __restrict__ P) {
    const int b = blockIdx.y;
    const int base = blockIdx.x * 2048;
    const unsigned short* L = leafG + (size_t)b * LEAF_IMG;
    unsigned short* Pb = P + (size_t)b * P_STRIDE;
    const int e0 = base + (int)threadIdx.x * 8;
    if (e0 >= P_STRIDE) return;

    unsigned rv[8], cv[8]; bool done[8]; int us[8];
    const int pr0 = e0 / 224, pc0 = e0 - pr0 * 224;
    int umax = -1;
#pragma unroll
    for (int t = 0; t < 8; ++t) {
        const int pc = pc0 + t;
        const int pr = pr0 + (pc >= 224 ? 1 : 0);
        rv[t] = (unsigned)pr;
        cv[t] = (unsigned)(pc >= 224 ? pc - 224 : pc);
        us[t] = min(222, 224 - pr);
        done[t] = false;
        umax = max(umax, us[t]);
    }
    for (int u = umax; u >= 0; --u) {
        const unsigned short* Lu = L + u * LEAF_SLOT;
        const int bot = 222 - u;
        bool all = true;
#pragma unroll
        for (int t = 0; t < 8; ++t) {
            if (!done[t] && u <= us[t]) {
                if ((int)rv[t] < bot) done[t] = true;
                else {
                    const unsigned q = Lu[__mul24((int)rv[t] - bot, 224) + (int)cv[t]];
                    rv[t] = q >> 8;
                    cv[t] = q & 255u;
                }
            }
            all = all && done[t];
        }
        if (all) break;
    }
    unsigned res[8];
#pragma unroll
    for (int t = 0; t < 8; ++t)
        res[t] = (unsigned)(__mul24((int)rv[t], 224) + (int)cv[t]);
    uint4 v;
    v.x = res[0] | (res[1] << 16);
    v.y = res[2] | (res[3] << 16);
    v.z = res[4] | (res[5] << 16);
    v.w = res[6] | (res[7] << 16);
    *(uint4*)(Pb + e0) = v;
}

// ---------------- blur1: f32 -> quantize u8 -> blur -> u8 plane (float4 loads) --------
__global__ __launch_bounds__(256) void blur1_kernel(const float* __restrict__ x,
                                                    unsigned char* __restrict__ img) {
    const int rb = blockIdx.x, c = blockIdx.y, b = blockIdx.z;
    const int y0 = rb * 8;
    __shared__ float A[12][WW];
    __shared__ float Bv[8][WW];
    const float* xp = x + ((size_t)(b * 3 + c)) * HH * WW;

    for (int l = threadIdx.x; l < 12 * 56; l += 256) {
        int r = l / 56, k4 = (l - r * 56) * 4;
        int gy = min(max(y0 + r - 2, 0), HH - 1);
        float4 v = *(const float4*)(xp + gy * WW + k4);
        A[r][k4]     = floorf(fminf(fmaxf(v.x * 255.0f, 0.0f), 255.0f));
        A[r][k4 + 1] = floorf(fminf(fmaxf(v.y * 255.0f, 0.0f), 255.0f));
        A[r][k4 + 2] = floorf(fminf(fmaxf(v.z * 255.0f, 0.0f), 255.0f));
        A[r][k4 + 3] = floorf(fminf(fmaxf(v.w * 255.0f, 0.0f), 255.0f));
    }
    __syncthreads();
    for (int l = threadIdx.x; l < 8 * WW; l += 256) {
        int r = l / WW, xx = l - r * WW;
        Bv[r][xx] = KW2 * A[r][xx] + KW1 * A[r + 1][xx] + KW0 * A[r + 2][xx]
                  + KW1 * A[r + 3][xx] + KW2 * A[r + 4][xx];
    }
    __syncthreads();
    unsigned char* op = img + ((size_t)(b * 3 + c)) * HH * WW;
    for (int l = threadIdx.x; l < 8 * WW; l += 256) {
        int r = l / WW, xx = l - r * WW;
        int c0 = max(xx - 2, 0), c1 = max(xx - 1, 0);
        int c3 = min(xx + 1, WW - 1), c4 = min(xx + 2, WW - 1);
        float s = KW2 * Bv[r][c0] + KW1 * Bv[r][c1] + KW0 * Bv[r][xx]
                + KW1 * Bv[r][c3] + KW2 * Bv[r][c4];
        op[(y0 + r) * WW + xx] = (unsigned char)floorf(s);
    }
}

// ---------------- blur2_apply: A[r][xx] = img[P[gy*224+xx]], uint4 P loads ------------
__global__ __launch_bounds__(256) void blur2_apply_kernel(const unsigned char* __restrict__ img,
                                                          const unsigned short* __restrict__ P,
                                                          float* __restrict__ out) {
    const int rb = blockIdx.x, c = blockIdx.y, b = blockIdx.z;
    const int y0 = rb * 8;
    __shared__ float A[12][WW];
    __shared__ float Bv[8][WW];
    const unsigned char* ip = img + ((size_t)(b * 3 + c)) * HH * WW;
    const unsigned short* Pp = P + (size_t)b * P_STRIDE;

    for (int l = threadIdx.x; l < 12 * 28; l += 256) {
        int r = l / 28, g8 = (l - r * 28) * 8;
        int gy = min(max(y0 + r - 2, 0), HH - 1);
        uint4 pe = *(const uint4*)(Pp + gy * WW + g8);   // 8 P entries, 16B coalesced
        A[r][g8]     = (float)ip[pe.x & 0xffffu];
        A[r][g8 + 1] = (float)ip[pe.x >> 16];
        A[r][g8 + 2] = (float)ip[pe.y & 0xffffu];
        A[r][g8 + 3] = (float)ip[pe.y >> 16];
        A[r][g8 + 4] = (float)ip[pe.z & 0xffffu];
        A[r][g8 + 5] = (float)ip[pe.z >> 16];
        A[r][g8 + 6] = (float)ip[pe.w & 0xffffu];
        A[r][g8 + 7] = (float)ip[pe.w >> 16];
    }
    __syncthreads();
    for (int l = threadIdx.x; l < 8 * WW; l += 256) {
        int r = l / WW, xx = l - r * WW;
        Bv[r][xx] = KW2 * A[r][xx] + KW1 * A[r + 1][xx] + KW0 * A[r + 2][xx]
                  + KW1 * A[r + 3][xx] + KW2 * A[r + 4][xx];
    }
    __syncthreads();
    float* op = out + ((size_t)(b * 3 + c)) * HH * WW;
    for (int l = threadIdx.x; l < 8 * WW; l += 256) {
        int r = l / WW, xx = l - r * WW;
        int c0 = max(xx - 2, 0), c1 = max(xx - 1, 0);
        int c3 = min(xx + 1, WW - 1), c4 = min(xx + 2, WW - 1);
        float s = KW2 * Bv[r][c0] + KW1 * Bv[r][c1] + KW0 * Bv[r][xx]
                + KW1 * Bv[r][c3] + KW2 * Bv[r][c4];
        s = fminf(fmaxf(s, 0.0f), 255.0f);
        op[(y0 + r) * WW + xx] = floorf(s) / 255.0f;
    }
}

// ================= fallback path (small d_ws) =================
__global__ __launch_bounds__(256) void apply_kernel(unsigned char* __restrict__ img,
                                                    const unsigned short* __restrict__ P) {
    const int plane = blockIdx.x;
    const int b = plane / 3;
    __shared__ __align__(16) unsigned char im[HH * WW];
    unsigned char* g = img + (size_t)plane * (HH * WW);
    for (int l = threadIdx.x; l < (HH * WW) / 16; l += 256)
        ((int4*)im)[l] = ((const int4*)g)[l];
    __syncthreads();
    const unsigned short* Pp = P + (size_t)b * P_STRIDE;
    for (int t = threadIdx.x; t < (HH * WW) / 8; t += 256) {
        uint4 pe = ((const uint4*)Pp)[t];
        unsigned e0 = pe.x & 0xffffu, e1 = pe.x >> 16;
        unsigned e2 = pe.y & 0xffffu, e3 = pe.y >> 16;
        unsigned e4 = pe.z & 0xffffu, e5 = pe.z >> 16;
        unsigned e6 = pe.w & 0xffffu, e7 = pe.w >> 16;
        unsigned lo = (unsigned)im[e0] | ((unsigned)im[e1] << 8)
                    | ((unsigned)im[e2] << 16) | ((unsigned)im[e3] << 24);
        unsigned hi = (unsigned)im[e4] | ((unsigned)im[e5] << 8)
                    | ((unsigned)im[e6] << 16) | ((unsigned)im[e7] << 24);
        ((uint2*)g)[t] = make_uint2(lo, hi);
    }
}

__global__ __launch_bounds__(256) void blur2_kernel(const unsigned char* __restrict__ img,
                                                    float* __restrict__ out) {
    const int rb = blockIdx.x, c = blockIdx.y, b = blockIdx.z;
    const int y0 = rb * 8;
    __shared__ float A[12][WW];
    __shared__ float Bv[8][WW];
    const unsigned char* ip = img + ((size_t)(b * 3 + c)) * HH * WW;

    for (int l = threadIdx.x; l < 12 * WW; l += 256) {
        int r = l / WW, xx = l - r * WW;
        int gy = min(max(y0 + r - 2, 0), HH - 1);
        A[r][xx] = (float)ip[gy * WW + xx];
    }
    __syncthreads();
    for (int l = threadIdx.x; l < 8 * WW; l += 256) {
        int r = l / WW, xx = l - r * WW;
        Bv[r][xx] = KW2 * A[r][xx] + KW1 * A[r + 1][xx] + KW0 * A[r + 2][xx]
                  + KW1 * A[r + 3][xx] + KW2 * A[r + 4][xx];
    }
    __syncthreads();
    float* op = out + ((size_t)(b * 3 + c)) * HH * WW;
    for (int l = threadIdx.x; l < 8 * WW; l += 256) {
        int r = l / WW, xx = l - r * WW;
        int c0 = max(xx - 2, 0), c1 = max(xx - 1, 0);
        int c3 = min(xx + 1, WW - 1), c4 = min(xx + 2, WW - 1);
        float s = KW2 * Bv[r][c0] + KW1 * Bv[r][c1] + KW0 * Bv[r][xx]
                + KW1 * Bv[r][c3] + KW2 * Bv[r][c4];
        s = fminf(fmaxf(s, 0.0f), 255.0f);
        op[(y0 + r) * WW + xx] = floorf(s) / 255.0f;
    }
}

extern "C" void kernel_launch(void* const* d_in, const int* in_sizes, int n_in,
                              void* d_out, int out_size, void* d_ws, size_t ws_size,
                              hipStream_t stream) {
    const float* x      = (const float*)d_in[0];
    const int*   deltas = (const int*)d_in[1];
    float*       out    = (float*)d_out;
    unsigned char* img  = (unsigned char*)d_ws;                     // 9,633,792 B

    const size_t imgBytes  = 9633792;
    const size_t leafBytes = (size_t)64 * LEAF_IMG * 2;             // 19,295,744 B
    const size_t pBytes    = (size_t)64 * P_STRIDE * 2;             //  6,422,528 B
    const bool big_ws = ws_size >= imgBytes + leafBytes + pBytes;

    if (big_ws) {
        unsigned short* leafG = (unsigned short*)(img + imgBytes);
        unsigned short* P     = (unsigned short*)(img + imgBytes + leafBytes);
        build_kernel<<<dim3(7, 64), 256, 0, stream>>>(deltas, leafG);
        chaseP_kernel<<<dim3(25, 64), 256, 0, stream>>>(leafG, P);      // leafG L2-hot
        blur1_kernel<<<dim3(28, 3, 64), 256, 0, stream>>>(x, img);
        blur2_apply_kernel<<<dim3(28, 3, 64), 256, 0, stream>>>(img, P, out);
    } else {
        // fallback: leafG + P in d_out scratch (dead before blur2's write)
        unsigned short* leafG = (unsigned short*)d_out;
        unsigned short* pF    = leafG + (size_t)64 * LEAF_IMG;
        build_kernel<<<dim3(7, 64), 256, 0, stream>>>(deltas, leafG);
        chaseP_kernel<<<dim3(25, 64), 256, 0, stream>>>(leafG, pF);
        blur1_kernel<<<dim3(28, 3, 64), 256, 0, stream>>>(x, img);
        apply_kernel<<<dim3(192), 256, 0, stream>>>(img, pF);
        blur2_kernel<<<dim3(28, 3, 64), 256, 0, stream>>>(img, out);
    }
}